// Round 2
// baseline (104.667 us; speedup 1.0000x reference)
//
#include <hip/hip_runtime.h>
#include <hip/hip_bf16.h>

#define BD 2
#define TT 1024
#define HH 8
#define DD 64
#define NLEV 11
#define RT 64
#define NT (TT / RT)        // 16 row tiles per (b,h)
#define NTRI (NT * (NT+1)/2) // 136 causal tile pairs per (b,h)
#define LSTR 72             // LDS row stride (bf16 elems): 144B, 16B-aligned, 2-way alias free

typedef __bf16 bf16;
typedef bf16 bf16x2 __attribute__((ext_vector_type(2)));
typedef bf16 bf16x4 __attribute__((ext_vector_type(4)));
typedef bf16 bf16x8 __attribute__((ext_vector_type(8)));
typedef float floatx4 __attribute__((ext_vector_type(4)));

// ---------------- Kernel 0: zero d_out (poisoned 0xAA by harness) ----------------
__global__ __launch_bounds__(256) void zero_kernel(float* __restrict__ out) {
    const int idx = blockIdx.x * 256 + threadIdx.x;
    float4 z = {0.f, 0.f, 0.f, 0.f};
    *(float4*)(out + (size_t)idx * 4) = z;
}

// ---------------- Kernel 1: cs[bh][t] = inclusive cumsum_t g[b,t,h] ----------------
__global__ __launch_bounds__(256) void cumsum_kernel(const float* __restrict__ g,
                                                     float* __restrict__ cs) {
    const int bh = blockIdx.x;           // 0..15
    const int b = bh >> 3, h = bh & 7;
    const int t = threadIdx.x;           // each owns 4 elems
    __shared__ float part[256];

    float v0[4];
    float s = 0.f;
#pragma unroll
    for (int u = 0; u < 4; ++u) {
        s += g[(b * TT + (t * 4 + u)) * HH + h];
        v0[u] = s;
    }
    part[t] = s;
    __syncthreads();
    float x = s;
    for (int off = 1; off < 256; off <<= 1) {
        float y = (t >= off) ? part[t - off] : 0.f;
        __syncthreads();
        x += y;
        part[t] = x;
        __syncthreads();
    }
    const float excl = x - s;
#pragma unroll
    for (int u = 0; u < 4; ++u) cs[bh * TT + t * 4 + u] = excl + v0[u];
}

// ---------------- Kernel 2: one block per (bh, rt, ct) causal tile ----------------
// 256 threads = 4 waves; wave w handles the 16-row strip m0 = w*16, all 64 cols.
// Output accumulated into pre-zeroed out via fp32 atomicAdd.
__global__ __launch_bounds__(256) void hattn_kernel(
    const float* __restrict__ q, const float* __restrict__ k,
    const float* __restrict__ v, const float* __restrict__ L,
    const float* __restrict__ cs, float* __restrict__ out) {
    const int blk = blockIdx.x;
    const int bh = blk / NTRI;
    const int rem = blk - bh * NTRI;
    // triangle decode: rem = rt*(rt+1)/2 + ct
    int rt = (int)((sqrtf(8.f * (float)rem + 1.f) - 1.f) * 0.5f);
    if (rt * (rt + 1) / 2 > rem) rt--;
    if ((rt + 1) * (rt + 2) / 2 <= rem) rt++;
    const int ct = rem - rt * (rt + 1) / 2;

    const int b = bh >> 3, h = bh & 7;
    const int tid = threadIdx.x;
    const int lane = tid & 63;
    const int wave = tid >> 6;       // 0..3
    const int m0 = wave * 16;
    const int lrow = lane & 15;
    const int lk = lane >> 4;        // 0..3

    __shared__ bf16 Qs[RT * LSTR];   // aliased: P overwrites Q (per-wave-private strips)
    __shared__ bf16 Ks[RT * LSTR];
    __shared__ bf16 Vt[RT * LSTR];   // Vt[p][j] = V[j][p]
    __shared__ float Lsh[7 * RT];    // diag: levels 0..6 ; off-diag: row 0 = L[lev]
    __shared__ float csRow[RT];
    __shared__ float csCol[RT];

    const bool diag = (rt == ct);

    // ---- stage Q and K tiles (fp32 -> bf16) ----
    {
        const int il = tid >> 2, d0 = (tid & 3) * 16;
        const float* qp = q + ((size_t)((b * TT + rt * RT + il) * HH) + h) * DD + d0;
        const float* kp = k + ((size_t)((b * TT + ct * RT + il) * HH) + h) * DD + d0;
#pragma unroll
        for (int u = 0; u < 16; u += 4) {
            float4 f = *(const float4*)(qp + u);
            bf16x4 w4 = {(bf16)f.x, (bf16)f.y, (bf16)f.z, (bf16)f.w};
            *(bf16x4*)&Qs[il * LSTR + d0 + u] = w4;
            float4 fk = *(const float4*)(kp + u);
            bf16x4 wk = {(bf16)fk.x, (bf16)fk.y, (bf16)fk.z, (bf16)fk.w};
            *(bf16x4*)&Ks[il * LSTR + d0 + u] = wk;
        }
    }
    // ---- stage V transposed: thread handles rows (2jp, 2jp+1), cols c0v..c0v+7 ----
    {
        const int jp = tid >> 3;            // 0..31
        const int c0v = (tid & 7) * 8;
        const float* vp0 = v + ((size_t)((b * TT + ct * RT + 2 * jp) * HH) + h) * DD + c0v;
        const float* vp1 = vp0 + HH * DD;
        float4 a0 = *(const float4*)(vp0);
        float4 a1 = *(const float4*)(vp0 + 4);
        float4 b0 = *(const float4*)(vp1);
        float4 b1 = *(const float4*)(vp1 + 4);
        float r0[8] = {a0.x, a0.y, a0.z, a0.w, a1.x, a1.y, a1.z, a1.w};
        float r1[8] = {b0.x, b0.y, b0.z, b0.w, b1.x, b1.y, b1.z, b1.w};
#pragma unroll
        for (int i = 0; i < 8; ++i) {
            bf16x2 w2 = {(bf16)r0[i], (bf16)r1[i]};
            *(bf16x2*)&Vt[(c0v + i) * LSTR + 2 * jp] = w2;
        }
    }
    // ---- stage cs and level scales ----
    if (tid < RT) csRow[tid] = cs[bh * TT + rt * RT + tid];
    else if (tid < 2 * RT) csCol[tid - RT] = cs[bh * TT + ct * RT + (tid - RT)];
    if (diag) {
        for (int u = tid; u < 7 * RT; u += 256)
            Lsh[u] = L[((size_t)bh * NLEV + (u >> 6)) * TT + rt * RT + (u & 63)];
    } else {
        const int lev = 38 - __clz(rt ^ ct);   // constant level for the whole tile
        if (tid < RT) Lsh[tid] = L[((size_t)bh * NLEV + lev) * TT + rt * RT + tid];
    }
    __syncthreads();

    // ---- S = Q K^T ----
    bf16x8 qa0 = *(bf16x8*)&Qs[(m0 + lrow) * LSTR + lk * 8];
    bf16x8 qa1 = *(bf16x8*)&Qs[(m0 + lrow) * LSTR + 32 + lk * 8];
    floatx4 sacc[4];
#pragma unroll
    for (int nb = 0; nb < 4; ++nb) {
        const int c0 = nb * 16;
        bf16x8 kb0 = *(bf16x8*)&Ks[(c0 + lrow) * LSTR + lk * 8];
        bf16x8 kb1 = *(bf16x8*)&Ks[(c0 + lrow) * LSTR + 32 + lk * 8];
        floatx4 acc = {0.f, 0.f, 0.f, 0.f};
        acc = __builtin_amdgcn_mfma_f32_16x16x32_bf16(qa0, kb0, acc, 0, 0, 0);
        acc = __builtin_amdgcn_mfma_f32_16x16x32_bf16(qa1, kb1, acc, 0, 0, 0);
        sacc[nb] = acc;
    }

    // ---- apply decay * level weight, write P into Qs (own-wave strip only) ----
    if (!diag) {
        float lw[4];
#pragma unroll
        for (int r = 0; r < 4; ++r) {
            const int rowl = m0 + lk * 4 + r;
            lw[r] = __expf(csRow[rowl]) * Lsh[rowl];
        }
#pragma unroll
        for (int nb = 0; nb < 4; ++nb) {
            const int c0 = nb * 16;
            const float ej = __expf(-csCol[c0 + lrow]);
#pragma unroll
            for (int r = 0; r < 4; ++r) {
                const int rowl = m0 + lk * 4 + r;
                Qs[rowl * LSTR + c0 + lrow] = (bf16)(sacc[nb][r] * lw[r] * ej);
            }
        }
    } else {
        float csr[4];
#pragma unroll
        for (int r = 0; r < 4; ++r) csr[r] = csRow[m0 + lk * 4 + r];
#pragma unroll
        for (int nb = 0; nb < 4; ++nb) {
            const int c0 = nb * 16;
            const int jl = c0 + lrow;
            const float csj = csCol[jl];
#pragma unroll
            for (int r = 0; r < 4; ++r) {
                const int rowl = m0 + lk * 4 + r;
                float wgt = 0.f;
                if (jl <= rowl) {
                    const int x = rowl ^ jl;
                    const int lev0 = x ? (32 - __clz(x)) : 0;
                    wgt = __expf(csr[r] - csj) * Lsh[lev0 * RT + rowl];
                }
                Qs[rowl * LSTR + jl] = (bf16)(sacc[nb][r] * wgt);
            }
        }
    }
    // No barrier: P strip is written and read only by this wave, and LDS ops
    // within a wave complete in program order.

    // ---- O = P V : A = P strip, B = Vt ----
    bf16x8 pa0 = *(bf16x8*)&Qs[(m0 + lrow) * LSTR + lk * 8];
    bf16x8 pa1 = *(bf16x8*)&Qs[(m0 + lrow) * LSTR + 32 + lk * 8];
    floatx4 O[4];
#pragma unroll
    for (int nb = 0; nb < 4; ++nb) {
        const int n0 = nb * 16;
        bf16x8 vb0 = *(bf16x8*)&Vt[(n0 + lrow) * LSTR + lk * 8];
        bf16x8 vb1 = *(bf16x8*)&Vt[(n0 + lrow) * LSTR + 32 + lk * 8];
        floatx4 acc = {0.f, 0.f, 0.f, 0.f};
        acc = __builtin_amdgcn_mfma_f32_16x16x32_bf16(pa0, vb0, acc, 0, 0, 0);
        acc = __builtin_amdgcn_mfma_f32_16x16x32_bf16(pa1, vb1, acc, 0, 0, 0);
        O[nb] = acc;
    }

    // ---- epilogue: atomic accumulate ----
#pragma unroll
    for (int r = 0; r < 4; ++r) {
        const int ig = rt * RT + m0 + lk * 4 + r;
        float* op = out + ((size_t)((b * TT + ig) * HH) + h) * DD;
#pragma unroll
        for (int nb = 0; nb < 4; ++nb)
            atomicAdd(op + nb * 16 + lrow, O[nb][r]);
    }
}

extern "C" void kernel_launch(void* const* d_in, const int* in_sizes, int n_in,
                              void* d_out, int out_size, void* d_ws, size_t ws_size,
                              hipStream_t stream) {
    const float* q = (const float*)d_in[0];
    const float* k = (const float*)d_in[1];
    const float* v = (const float*)d_in[2];
    const float* g = (const float*)d_in[3];
    const float* L = (const float*)d_in[4];
    float* out = (float*)d_out;
    float* cs = (float*)d_ws;  // 16*1024 floats

    zero_kernel<<<(BD * TT * HH * DD) / (256 * 4), 256, 0, stream>>>(out);
    cumsum_kernel<<<BD * HH, 256, 0, stream>>>(g, cs);
    hattn_kernel<<<BD * HH * NTRI, 256, 0, stream>>>(q, k, v, L, cs, out);
}

// Round 3
// 94.693 us; speedup vs baseline: 1.1053x; 1.1053x over previous
//
#include <hip/hip_runtime.h>
#include <hip/hip_bf16.h>

#define BD 2
#define TT 1024
#define HH 8
#define DD 64
#define NLEV 11
#define RT 64
#define NT 16               // row tiles per (b,h)
#define NCHUNK 72           // sum over rt of (rt/2 + 1)  (ct-pairs per bh)
#define LSTR 72             // LDS row stride (bf16): 144B, 16B-aligned, 2-way alias free

typedef __bf16 bf16;
typedef bf16 bf16x2 __attribute__((ext_vector_type(2)));
typedef bf16 bf16x4 __attribute__((ext_vector_type(4)));
typedef bf16 bf16x8 __attribute__((ext_vector_type(8)));
typedef float floatx4 __attribute__((ext_vector_type(4)));

// chunk tables: chunk c (0..71) -> row tile; CBASE[rt] = first chunk of rt
__device__ __constant__ unsigned char RT_OF[NCHUNK] = {
    0, 1, 2, 2, 3, 3, 4, 4, 4, 5, 5, 5, 6, 6, 6, 6,
    7, 7, 7, 7, 8, 8, 8, 8, 8, 9, 9, 9, 9, 9,
    10, 10, 10, 10, 10, 10, 11, 11, 11, 11, 11, 11,
    12, 12, 12, 12, 12, 12, 12, 13, 13, 13, 13, 13, 13, 13,
    14, 14, 14, 14, 14, 14, 14, 14, 15, 15, 15, 15, 15, 15, 15, 15};
__device__ __constant__ int CBASE[NT] = {0, 1, 2, 4, 6, 9, 12, 16, 20, 25, 30, 36, 42, 49, 56, 64};

// ---------------- Kernel 1: cs[bh][t] = inclusive cumsum_t g[b,t,h] ----------------
__global__ __launch_bounds__(256) void cumsum_kernel(const float* __restrict__ g,
                                                     float* __restrict__ cs) {
    const int bh = blockIdx.x;           // 0..15
    const int b = bh >> 3, h = bh & 7;
    const int t = threadIdx.x;           // each owns 4 elems
    __shared__ float part[256];

    float v0[4];
    float s = 0.f;
#pragma unroll
    for (int u = 0; u < 4; ++u) {
        s += g[(b * TT + (t * 4 + u)) * HH + h];
        v0[u] = s;
    }
    part[t] = s;
    __syncthreads();
    float x = s;
    for (int off = 1; off < 256; off <<= 1) {
        float y = (t >= off) ? part[t - off] : 0.f;
        __syncthreads();
        x += y;
        part[t] = x;
        __syncthreads();
    }
    const float excl = x - s;
#pragma unroll
    for (int u = 0; u < 4; ++u) cs[bh * TT + t * 4 + u] = excl + v0[u];
}

// ---------------- Kernel 2: one block per (bh, chunk) = (bh, rt, ct-pair) ----------
// 256 threads = 4 waves; wave w owns 16-row strip m0 = w*16 of the 64-row Q tile.
// Partial O tile (64x64 fp32) stored to ws; no atomics.
__global__ __launch_bounds__(256) void hattn_kernel(
    const float* __restrict__ q, const float* __restrict__ k,
    const float* __restrict__ v, const float* __restrict__ L,
    const float* __restrict__ cs, float* __restrict__ part) {
    const int blk = blockIdx.x;
    const int bh = blk / NCHUNK;
    const int c = blk - bh * NCHUNK;
    const int rt = RT_OF[c];
    const int ct0 = 2 * (c - CBASE[rt]);
    const int ctend = (ct0 + 1 <= rt) ? (ct0 + 1) : rt;

    const int b = bh >> 3, h = bh & 7;
    const int tid = threadIdx.x;
    const int lane = tid & 63;
    const int wave = tid >> 6;       // 0..3
    const int m0 = wave * 16;
    const int lrow = lane & 15;
    const int lk = lane >> 4;        // 0..3

    __shared__ bf16 Qs[RT * LSTR];   // Q staged once; later aliased as per-wave P scratch
    __shared__ bf16 Ks[RT * LSTR];
    __shared__ bf16 Vt[RT * LSTR];   // Vt[p][j] = V[j][p]
    __shared__ float Lsh[7 * RT];    // off-diag: row 0 only; diag: levels 0..6
    __shared__ float csRow[RT];
    __shared__ float csCol[RT];

    // ---- stage Q tile (fp32 -> bf16) + csRow ----
    {
        const int il = tid >> 2, d0 = (tid & 3) * 16;
        const float* qp = q + ((size_t)((b * TT + rt * RT + il) * HH) + h) * DD + d0;
#pragma unroll
        for (int u = 0; u < 16; u += 4) {
            float4 f = *(const float4*)(qp + u);
            bf16x4 w4 = {(bf16)f.x, (bf16)f.y, (bf16)f.z, (bf16)f.w};
            *(bf16x4*)&Qs[il * LSTR + d0 + u] = w4;
        }
    }
    if (tid < RT) csRow[tid] = cs[bh * TT + rt * RT + tid];
    __syncthreads();

    // Q fragments live in registers for the whole block; Qs becomes P scratch.
    const bf16x8 qa0 = *(bf16x8*)&Qs[(m0 + lrow) * LSTR + lk * 8];
    const bf16x8 qa1 = *(bf16x8*)&Qs[(m0 + lrow) * LSTR + 32 + lk * 8];
    float csr[4];
#pragma unroll
    for (int r = 0; r < 4; ++r) csr[r] = csRow[m0 + lk * 4 + r];

    floatx4 O[4];
#pragma unroll
    for (int nb = 0; nb < 4; ++nb) O[nb] = (floatx4){0.f, 0.f, 0.f, 0.f};

    for (int ct = ct0; ct <= ctend; ++ct) {
        const bool diag = (ct == rt);
        __syncthreads();  // prior-iteration readers of Ks/Vt/Lsh/csCol are done
        // ---- stage K tile ----
        {
            const int il = tid >> 2, d0 = (tid & 3) * 16;
            const float* kp = k + ((size_t)((b * TT + ct * RT + il) * HH) + h) * DD + d0;
#pragma unroll
            for (int u = 0; u < 16; u += 4) {
                float4 fk = *(const float4*)(kp + u);
                bf16x4 wk = {(bf16)fk.x, (bf16)fk.y, (bf16)fk.z, (bf16)fk.w};
                *(bf16x4*)&Ks[il * LSTR + d0 + u] = wk;
            }
        }
        // ---- stage V transposed ----
        {
            const int jp = tid >> 3;            // 0..31 (row pair)
            const int c0v = (tid & 7) * 8;
            const float* vp0 = v + ((size_t)((b * TT + ct * RT + 2 * jp) * HH) + h) * DD + c0v;
            const float* vp1 = vp0 + HH * DD;
            float4 a0 = *(const float4*)(vp0);
            float4 a1 = *(const float4*)(vp0 + 4);
            float4 b0 = *(const float4*)(vp1);
            float4 b1 = *(const float4*)(vp1 + 4);
            float r0[8] = {a0.x, a0.y, a0.z, a0.w, a1.x, a1.y, a1.z, a1.w};
            float r1[8] = {b0.x, b0.y, b0.z, b0.w, b1.x, b1.y, b1.z, b1.w};
#pragma unroll
            for (int i = 0; i < 8; ++i) {
                bf16x2 w2 = {(bf16)r0[i], (bf16)r1[i]};
                *(bf16x2*)&Vt[(c0v + i) * LSTR + 2 * jp] = w2;
            }
        }
        if (tid < RT) csCol[tid] = cs[bh * TT + ct * RT + tid];
        if (diag) {
            for (int u = tid; u < 7 * RT; u += 256)
                Lsh[u] = L[((size_t)bh * NLEV + (u >> 6)) * TT + rt * RT + (u & 63)];
        } else if (tid < RT) {
            const int lev = 38 - __clz(rt ^ ct);   // constant level for the whole tile
            Lsh[tid] = L[((size_t)bh * NLEV + lev) * TT + rt * RT + tid];
        }
        __syncthreads();

        // ---- S = Q K^T ----
        floatx4 sacc[4];
#pragma unroll
        for (int nb = 0; nb < 4; ++nb) {
            const int c0 = nb * 16;
            bf16x8 kb0 = *(bf16x8*)&Ks[(c0 + lrow) * LSTR + lk * 8];
            bf16x8 kb1 = *(bf16x8*)&Ks[(c0 + lrow) * LSTR + 32 + lk * 8];
            floatx4 acc = {0.f, 0.f, 0.f, 0.f};
            acc = __builtin_amdgcn_mfma_f32_16x16x32_bf16(qa0, kb0, acc, 0, 0, 0);
            acc = __builtin_amdgcn_mfma_f32_16x16x32_bf16(qa1, kb1, acc, 0, 0, 0);
            sacc[nb] = acc;
        }

        // ---- apply decay * level weight, write P into Qs (own-wave strip only) ----
        if (!diag) {
            float lw[4];
#pragma unroll
            for (int r = 0; r < 4; ++r) {
                const int rowl = m0 + lk * 4 + r;
                lw[r] = __expf(csr[r]) * Lsh[rowl];
            }
#pragma unroll
            for (int nb = 0; nb < 4; ++nb) {
                const int c0 = nb * 16;
                const float ej = __expf(-csCol[c0 + lrow]);
#pragma unroll
                for (int r = 0; r < 4; ++r) {
                    const int rowl = m0 + lk * 4 + r;
                    Qs[rowl * LSTR + c0 + lrow] = (bf16)(sacc[nb][r] * lw[r] * ej);
                }
            }
        } else {
#pragma unroll
            for (int nb = 0; nb < 4; ++nb) {
                const int c0 = nb * 16;
                const int jl = c0 + lrow;
                const float csj = csCol[jl];
#pragma unroll
                for (int r = 0; r < 4; ++r) {
                    const int rowl = m0 + lk * 4 + r;
                    float wgt = 0.f;
                    if (jl <= rowl) {
                        const int x = rowl ^ jl;
                        const int lev0 = x ? (32 - __clz(x)) : 0;
                        wgt = __expf(csr[r] - csj) * Lsh[lev0 * RT + rowl];
                    }
                    Qs[rowl * LSTR + jl] = (bf16)(sacc[nb][r] * wgt);
                }
            }
        }
        // No barrier: the P strip is written and read only by this wave (in-order LDS).

        // ---- O += P V ----
        bf16x8 pa0 = *(bf16x8*)&Qs[(m0 + lrow) * LSTR + lk * 8];
        bf16x8 pa1 = *(bf16x8*)&Qs[(m0 + lrow) * LSTR + 32 + lk * 8];
#pragma unroll
        for (int nb = 0; nb < 4; ++nb) {
            const int n0 = nb * 16;
            bf16x8 vb0 = *(bf16x8*)&Vt[(n0 + lrow) * LSTR + lk * 8];
            bf16x8 vb1 = *(bf16x8*)&Vt[(n0 + lrow) * LSTR + 32 + lk * 8];
            O[nb] = __builtin_amdgcn_mfma_f32_16x16x32_bf16(pa0, vb0, O[nb], 0, 0, 0);
            O[nb] = __builtin_amdgcn_mfma_f32_16x16x32_bf16(pa1, vb1, O[nb], 0, 0, 0);
        }
    }

    // ---- epilogue: plain stores of the partial tile ----
    float* slot = part + (size_t)(bh * NCHUNK + c) * 4096;
#pragma unroll
    for (int r = 0; r < 4; ++r) {
        const int rowl = m0 + lk * 4 + r;
#pragma unroll
        for (int nb = 0; nb < 4; ++nb)
            slot[rowl * 64 + nb * 16 + lrow] = O[nb][r];
    }
}

// ---------------- Kernel 3: out = sum of partial tiles ----------------
__global__ __launch_bounds__(256) void reduce_kernel(const float* __restrict__ part,
                                                     float* __restrict__ out) {
    const int e = blockIdx.x * 256 + threadIdx.x;   // flat output element
    const int d = e & 63;
    const int h = (e >> 6) & 7;
    const int t = (e >> 9) & 1023;
    const int b = e >> 19;
    const int rt = t >> 6, i = t & 63;
    const int bh = b * 8 + h;
    const float* p = part + (size_t)(bh * NCHUNK + CBASE[rt]) * 4096 + i * 64 + d;
    const int n = (rt >> 1) + 1;
    float s = 0.f;
    for (int cc = 0; cc < n; ++cc) s += p[(size_t)cc * 4096];
    out[e] = s;
}

extern "C" void kernel_launch(void* const* d_in, const int* in_sizes, int n_in,
                              void* d_out, int out_size, void* d_ws, size_t ws_size,
                              hipStream_t stream) {
    const float* q = (const float*)d_in[0];
    const float* k = (const float*)d_in[1];
    const float* v = (const float*)d_in[2];
    const float* g = (const float*)d_in[3];
    const float* L = (const float*)d_in[4];
    float* out = (float*)d_out;
    float* cs = (float*)d_ws;                       // 16*1024 floats
    float* part = (float*)d_ws + 16384;             // 16*72*4096 floats (~18.9 MB)

    cumsum_kernel<<<BD * HH, 256, 0, stream>>>(g, cs);
    hattn_kernel<<<BD * HH * NCHUNK, 256, 0, stream>>>(q, k, v, L, cs, part);
    reduce_kernel<<<(BD * TT * HH * DD) / 256, 256, 0, stream>>>(part, out);
}

// Round 4
// 91.494 us; speedup vs baseline: 1.1440x; 1.0350x over previous
//
#include <hip/hip_runtime.h>
#include <hip/hip_bf16.h>

#define BD 2
#define TT 1024
#define HH 8
#define DD 64
#define NLEV 11
#define RT 64
#define NT 16
#define LSTR 72            // LDS row stride (bf16): 144B, 16B-aligned, 2-way alias free
#define NSLOT 23           // per bh: 16 H1 + 4 H2 + 2 H4 + 1 H8
#define SLAB 4096          // floats per 64x64 slab

typedef __bf16 bf16;
typedef bf16 bf16x2 __attribute__((ext_vector_type(2)));
typedef bf16 bf16x4 __attribute__((ext_vector_type(4)));
typedef bf16 bf16x8 __attribute__((ext_vector_type(8)));
typedef float floatx4 __attribute__((ext_vector_type(4)));

// ---------------- Kernel 1: cs[bh][t] = inclusive cumsum_t g[b,t,h] ----------------
__global__ __launch_bounds__(256) void cumsum_kernel(const float* __restrict__ g,
                                                     float* __restrict__ cs) {
    const int bh = blockIdx.x;           // 0..15
    const int b = bh >> 3, h = bh & 7;
    const int t = threadIdx.x;           // each owns 4 elems
    __shared__ float part[256];

    float v0[4];
    float s = 0.f;
#pragma unroll
    for (int u = 0; u < 4; ++u) {
        s += g[(b * TT + (t * 4 + u)) * HH + h];
        v0[u] = s;
    }
    part[t] = s;
    __syncthreads();
    float x = s;
    for (int off = 1; off < 256; off <<= 1) {
        float y = (t >= off) ? part[t - off] : 0.f;
        __syncthreads();
        x += y;
        part[t] = x;
        __syncthreads();
    }
    const float excl = x - s;
#pragma unroll
    for (int u = 0; u < 4; ++u) cs[bh * TT + t * 4 + u] = excl + v0[u];
}

// ---------------- Kernel 2: build per-tile KV summaries ----------------------------
// H1[c] (stored transposed, [d][p]) = sum_{j in tile c} exp(E_c - cs_j) * v_j[d]*k_j[p]
// grid = 16 bh * 16 tiles; 256 threads = 4 waves, wave w owns d-strip [16w,16w+16).
__global__ __launch_bounds__(256) void buildh_kernel(
    const float* __restrict__ k, const float* __restrict__ v,
    const float* __restrict__ cs, float* __restrict__ H) {
    const int blk = blockIdx.x;
    const int bh = blk >> 4, c = blk & 15;
    const int b = bh >> 3, h = bh & 7;
    const int tid = threadIdx.x;
    const int lane = tid & 63, wave = tid >> 6;
    const int m0 = wave * 16;           // d-strip
    const int lrow = lane & 15, lk = lane >> 4;

    __shared__ bf16 Kt[RT * LSTR];      // Kt[p][j] = exp(E_c - cs_j) * k_j[p]
    __shared__ bf16 Vt[RT * LSTR];      // Vt[d][j] = v_j[d]

    const float Ec = cs[bh * TT + c * RT + 63];
    {
        const int jp = tid >> 3, p0 = (tid & 7) * 8;   // rows (2jp,2jp+1), 8 dims
        const int j0 = c * RT + 2 * jp;
        const float* kp0 = k + ((size_t)((b * TT + j0) * HH) + h) * DD + p0;
        const float* kp1 = kp0 + HH * DD;
        const float* vp0 = v + ((size_t)((b * TT + j0) * HH) + h) * DD + p0;
        const float* vp1 = vp0 + HH * DD;
        const float w0 = __expf(Ec - cs[bh * TT + j0]);
        const float w1 = __expf(Ec - cs[bh * TT + j0 + 1]);
        float4 ka0 = *(const float4*)kp0, ka1 = *(const float4*)(kp0 + 4);
        float4 kb0 = *(const float4*)kp1, kb1 = *(const float4*)(kp1 + 4);
        float4 va0 = *(const float4*)vp0, va1 = *(const float4*)(vp0 + 4);
        float4 vb0 = *(const float4*)vp1, vb1 = *(const float4*)(vp1 + 4);
        float kr0[8] = {ka0.x, ka0.y, ka0.z, ka0.w, ka1.x, ka1.y, ka1.z, ka1.w};
        float kr1[8] = {kb0.x, kb0.y, kb0.z, kb0.w, kb1.x, kb1.y, kb1.z, kb1.w};
        float vr0[8] = {va0.x, va0.y, va0.z, va0.w, va1.x, va1.y, va1.z, va1.w};
        float vr1[8] = {vb0.x, vb0.y, vb0.z, vb0.w, vb1.x, vb1.y, vb1.z, vb1.w};
#pragma unroll
        for (int i2 = 0; i2 < 8; ++i2) {
            bf16x2 kk = {(bf16)(kr0[i2] * w0), (bf16)(kr1[i2] * w1)};
            *(bf16x2*)&Kt[(p0 + i2) * LSTR + 2 * jp] = kk;
            bf16x2 vv = {(bf16)vr0[i2], (bf16)vr1[i2]};
            *(bf16x2*)&Vt[(p0 + i2) * LSTR + 2 * jp] = vv;
        }
    }
    __syncthreads();

    bf16x8 a0 = *(bf16x8*)&Vt[(m0 + lrow) * LSTR + lk * 8];
    bf16x8 a1 = *(bf16x8*)&Vt[(m0 + lrow) * LSTR + 32 + lk * 8];
    float* slab = H + (size_t)(bh * NSLOT + c) * SLAB;
#pragma unroll
    for (int nb = 0; nb < 4; ++nb) {
        bf16x8 b0 = *(bf16x8*)&Kt[(nb * 16 + lrow) * LSTR + lk * 8];
        bf16x8 b1 = *(bf16x8*)&Kt[(nb * 16 + lrow) * LSTR + 32 + lk * 8];
        floatx4 acc = {0.f, 0.f, 0.f, 0.f};
        acc = __builtin_amdgcn_mfma_f32_16x16x32_bf16(a0, b0, acc, 0, 0, 0);
        acc = __builtin_amdgcn_mfma_f32_16x16x32_bf16(a1, b1, acc, 0, 0, 0);
#pragma unroll
        for (int r = 0; r < 4; ++r)
            slab[(m0 + lk * 4 + r) * 64 + nb * 16 + lrow] = acc[r];
    }
}

// ---------------- Kernel 3: combine H1 into larger-range slabs ----------------------
// slots 16..19: H2 (tiles 4m..4m+1), 20..21: H4 (8m..8m+3), 22: H8 (0..7)
__global__ __launch_bounds__(256) void combine_kernel(float* __restrict__ H,
                                                      const float* __restrict__ cs) {
    const int blk = blockIdx.x;
    const int bh = blk / 7, s7 = blk - bh * 7;
    int t0, n, slot;
    if (s7 < 4)      { t0 = 4 * s7;       n = 2; slot = 16 + s7; }
    else if (s7 < 6) { t0 = 8 * (s7 - 4); n = 4; slot = 20 + (s7 - 4); }
    else             { t0 = 0;            n = 8; slot = 22; }
    const float Eref = cs[bh * TT + (t0 + n - 1) * RT + 63];
    const int e0 = threadIdx.x * 16;
    float acc[16];
#pragma unroll
    for (int u = 0; u < 16; ++u) acc[u] = 0.f;
    for (int t = 0; t < n; ++t) {
        const float w = __expf(Eref - cs[bh * TT + (t0 + t) * RT + 63]);  // <= 1
        const float* src = H + (size_t)(bh * NSLOT + t0 + t) * SLAB + e0;
#pragma unroll
        for (int u = 0; u < 4; ++u) {
            float4 f = *(const float4*)(src + 4 * u);
            acc[4 * u] += w * f.x; acc[4 * u + 1] += w * f.y;
            acc[4 * u + 2] += w * f.z; acc[4 * u + 3] += w * f.w;
        }
    }
    float* dst = H + (size_t)(bh * NSLOT + slot) * SLAB + e0;
#pragma unroll
    for (int u = 0; u < 4; ++u) {
        float4 f = {acc[4 * u], acc[4 * u + 1], acc[4 * u + 2], acc[4 * u + 3]};
        *(float4*)(dst + 4 * u) = f;
    }
}

// ---------------- Kernel 4: output pass -------------------------------------------
// grid = 16 bh * 16 rt * 2 row-halves; 128 threads = 2 waves (16-row strips).
// out_half = diag(direct, levels 0..6) + sum over set bits s of rt:
//            diag(L[7+s,i] * exp(cs_i - Eref)) * Q * Htilde(range)
__global__ __launch_bounds__(128) void out_kernel(
    const float* __restrict__ q, const float* __restrict__ k,
    const float* __restrict__ v, const float* __restrict__ L,
    const float* __restrict__ cs, const float* __restrict__ H,
    float* __restrict__ out) {
    const int blk = blockIdx.x;
    const int half = blk & 1;
    const int rt = (blk >> 1) & 15;
    const int bh = blk >> 5;
    const int b = bh >> 3, h = bh & 7;
    const int tid = threadIdx.x;        // 0..127
    const int lane = tid & 63, wave = tid >> 6;
    const int m0 = wave * 16;           // local row strip (within 32-row half)
    const int lrow = lane & 15, lk = lane >> 4;
    const int rbase = half * 32;        // tile-local row offset

    __shared__ bf16 Qs[32 * LSTR];
    __shared__ bf16 Ks[64 * LSTR];
    __shared__ bf16 Vt[64 * LSTR];      // Vt[d][j]
    __shared__ bf16 Hs[64 * LSTR];      // staged slab [d][p], reused per level
    __shared__ bf16 Ps[32 * LSTR];
    __shared__ float Lsh[7 * 32];
    __shared__ float Lw[32];
    __shared__ float csRow[32];
    __shared__ float csCol[64];

    // ---- stage Q (own 32 rows) ----
    {
        const int il = tid >> 2, d0 = (tid & 3) * 16;
        const float* qp = q + ((size_t)((b * TT + rt * RT + rbase + il) * HH) + h) * DD + d0;
#pragma unroll
        for (int u = 0; u < 16; u += 4) {
            float4 f = *(const float4*)(qp + u);
            bf16x4 w4 = {(bf16)f.x, (bf16)f.y, (bf16)f.z, (bf16)f.w};
            *(bf16x4*)&Qs[il * LSTR + d0 + u] = w4;
        }
    }
    // ---- stage diag K (all 64 rows) ----
    {
        const int il = tid >> 1, d0 = (tid & 1) * 32;
        const float* kp = k + ((size_t)((b * TT + rt * RT + il) * HH) + h) * DD + d0;
#pragma unroll
        for (int u = 0; u < 32; u += 4) {
            float4 f = *(const float4*)(kp + u);
            bf16x4 w4 = {(bf16)f.x, (bf16)f.y, (bf16)f.z, (bf16)f.w};
            *(bf16x4*)&Ks[il * LSTR + d0 + u] = w4;
        }
    }
    // ---- stage diag V transposed ----
    {
        const int jp = tid >> 2, p0 = (tid & 3) * 16;  // rows (2jp,2jp+1), 16 dims
        const float* vp0 = v + ((size_t)((b * TT + rt * RT + 2 * jp) * HH) + h) * DD + p0;
        const float* vp1 = vp0 + HH * DD;
        float r0[16], r1[16];
#pragma unroll
        for (int u = 0; u < 4; ++u) {
            float4 f = *(const float4*)(vp0 + 4 * u);
            r0[4 * u] = f.x; r0[4 * u + 1] = f.y; r0[4 * u + 2] = f.z; r0[4 * u + 3] = f.w;
            float4 g2 = *(const float4*)(vp1 + 4 * u);
            r1[4 * u] = g2.x; r1[4 * u + 1] = g2.y; r1[4 * u + 2] = g2.z; r1[4 * u + 3] = g2.w;
        }
#pragma unroll
        for (int i2 = 0; i2 < 16; ++i2) {
            bf16x2 w2 = {(bf16)r0[i2], (bf16)r1[i2]};
            *(bf16x2*)&Vt[(p0 + i2) * LSTR + 2 * jp] = w2;
        }
    }
    if (tid < 32) csRow[tid] = cs[bh * TT + rt * RT + rbase + tid];
    else if (tid < 96) csCol[tid - 32] = cs[bh * TT + rt * RT + (tid - 32)];
    for (int u = tid; u < 7 * 32; u += 128)
        Lsh[u] = L[((size_t)bh * NLEV + (u >> 5)) * TT + rt * RT + rbase + (u & 31)];
    __syncthreads();

    bf16x8 qa0 = *(bf16x8*)&Qs[(m0 + lrow) * LSTR + lk * 8];
    bf16x8 qa1 = *(bf16x8*)&Qs[(m0 + lrow) * LSTR + 32 + lk * 8];
    float csr[4];
#pragma unroll
    for (int r = 0; r < 4; ++r) csr[r] = csRow[m0 + lk * 4 + r];

    // ---- diagonal: S = Q K^T ----
    floatx4 sacc[4];
#pragma unroll
    for (int nb = 0; nb < 4; ++nb) {
        bf16x8 b0 = *(bf16x8*)&Ks[(nb * 16 + lrow) * LSTR + lk * 8];
        bf16x8 b1 = *(bf16x8*)&Ks[(nb * 16 + lrow) * LSTR + 32 + lk * 8];
        floatx4 acc = {0.f, 0.f, 0.f, 0.f};
        acc = __builtin_amdgcn_mfma_f32_16x16x32_bf16(qa0, b0, acc, 0, 0, 0);
        acc = __builtin_amdgcn_mfma_f32_16x16x32_bf16(qa1, b1, acc, 0, 0, 0);
        sacc[nb] = acc;
    }
    // ---- weight (levels 0..6, per-element) -> P ----
#pragma unroll
    for (int nb = 0; nb < 4; ++nb) {
        const int jl = nb * 16 + lrow;       // tile-local col
        const float csj = csCol[jl];
#pragma unroll
        for (int r = 0; r < 4; ++r) {
            const int rl = m0 + lk * 4 + r;  // local row (0..31)
            const int il64 = rbase + rl;     // tile-local row
            float wgt = 0.f;
            if (jl <= il64) {
                const int x = il64 ^ jl;
                const int lev0 = x ? (32 - __clz(x)) : 0;
                wgt = __expf(csr[r] - csj) * Lsh[lev0 * 32 + rl];
            }
            Ps[rl * LSTR + jl] = (bf16)(sacc[nb][r] * wgt);
        }
    }
    // own-wave strip: no barrier needed (in-order LDS within a wave)
    bf16x8 pa0 = *(bf16x8*)&Ps[(m0 + lrow) * LSTR + lk * 8];
    bf16x8 pa1 = *(bf16x8*)&Ps[(m0 + lrow) * LSTR + 32 + lk * 8];
    floatx4 O[4];
#pragma unroll
    for (int nb = 0; nb < 4; ++nb) {
        bf16x8 b0 = *(bf16x8*)&Vt[(nb * 16 + lrow) * LSTR + lk * 8];
        bf16x8 b1 = *(bf16x8*)&Vt[(nb * 16 + lrow) * LSTR + 32 + lk * 8];
        floatx4 acc = {0.f, 0.f, 0.f, 0.f};
        acc = __builtin_amdgcn_mfma_f32_16x16x32_bf16(pa0, b0, acc, 0, 0, 0);
        acc = __builtin_amdgcn_mfma_f32_16x16x32_bf16(pa1, b1, acc, 0, 0, 0);
        O[nb] = acc;
    }

    // ---- hierarchical levels 7..10 via precomputed slabs ----
    for (int s = 0; s < 4; ++s) {
        if (!((rt >> s) & 1)) continue;               // block-uniform
        int slot, reft;
        if (s == 0)      { slot = rt - 1;          reft = rt - 1; }
        else if (s == 1) { slot = 16 + (rt >> 2);  reft = (rt & ~1) - 1; }
        else if (s == 2) { slot = 20 + (rt >> 3);  reft = (rt & ~3) - 1; }
        else             { slot = 22;              reft = 7; }
        __syncthreads();   // prior Hs readers done
        {
            const int il = tid >> 1, p0 = (tid & 1) * 32;
            const float* hp = H + (size_t)(bh * NSLOT + slot) * SLAB + il * 64 + p0;
#pragma unroll
            for (int u = 0; u < 32; u += 4) {
                float4 f = *(const float4*)(hp + u);
                bf16x4 w4 = {(bf16)f.x, (bf16)f.y, (bf16)f.z, (bf16)f.w};
                *(bf16x4*)&Hs[il * LSTR + p0 + u] = w4;
            }
        }
        if (tid < 32) Lw[tid] = L[((size_t)bh * NLEV + (7 + s)) * TT + rt * RT + rbase + tid];
        __syncthreads();
        const float Eref = cs[bh * TT + reft * RT + 63];
        float wr[4];
#pragma unroll
        for (int r = 0; r < 4; ++r)
            wr[r] = Lw[m0 + lk * 4 + r] * __expf(csr[r] - Eref);
#pragma unroll
        for (int nb = 0; nb < 4; ++nb) {
            bf16x8 b0 = *(bf16x8*)&Hs[(nb * 16 + lrow) * LSTR + lk * 8];
            bf16x8 b1 = *(bf16x8*)&Hs[(nb * 16 + lrow) * LSTR + 32 + lk * 8];
            floatx4 acc = {0.f, 0.f, 0.f, 0.f};
            acc = __builtin_amdgcn_mfma_f32_16x16x32_bf16(qa0, b0, acc, 0, 0, 0);
            acc = __builtin_amdgcn_mfma_f32_16x16x32_bf16(qa1, b1, acc, 0, 0, 0);
#pragma unroll
            for (int r = 0; r < 4; ++r) O[nb][r] += wr[r] * acc[r];
        }
    }

    // ---- epilogue ----
#pragma unroll
    for (int r = 0; r < 4; ++r) {
        const int ig = rt * RT + rbase + m0 + lk * 4 + r;
        float* op = out + ((size_t)((b * TT + ig) * HH) + h) * DD;
#pragma unroll
        for (int nb = 0; nb < 4; ++nb)
            op[nb * 16 + lrow] = O[nb][r];
    }
}

extern "C" void kernel_launch(void* const* d_in, const int* in_sizes, int n_in,
                              void* d_out, int out_size, void* d_ws, size_t ws_size,
                              hipStream_t stream) {
    const float* q = (const float*)d_in[0];
    const float* k = (const float*)d_in[1];
    const float* v = (const float*)d_in[2];
    const float* g = (const float*)d_in[3];
    const float* L = (const float*)d_in[4];
    float* out = (float*)d_out;
    float* cs = (float*)d_ws;                    // 16*1024 floats
    float* H = (float*)d_ws + 16384;             // 16*23*4096 floats (~6 MB)

    cumsum_kernel<<<BD * HH, 256, 0, stream>>>(g, cs);
    buildh_kernel<<<BD * HH * NT, 256, 0, stream>>>(k, v, cs, H);
    combine_kernel<<<BD * HH * 7, 256, 0, stream>>>(H, cs);
    out_kernel<<<BD * HH * NT * 2, 128, 0, stream>>>(q, k, v, L, cs, H, out);
}

// Round 5
// 90.744 us; speedup vs baseline: 1.1534x; 1.0083x over previous
//
#include <hip/hip_runtime.h>
#include <hip/hip_bf16.h>

#define BD 2
#define TT 1024
#define HH 8
#define DD 64
#define NLEV 11
#define RT 64
#define NT 16
#define LSTR 72            // LDS row stride (bf16): 144B = 16B-aligned, 2-way alias free
#define NSLOT 23           // per bh: 16 H1 + 4 H2 + 2 H4 + 1 H8
#define SLAB 4096          // floats per 64x64 slab

typedef __bf16 bf16;
typedef bf16 bf16x2 __attribute__((ext_vector_type(2)));
typedef bf16 bf16x4 __attribute__((ext_vector_type(4)));
typedef bf16 bf16x8 __attribute__((ext_vector_type(8)));
typedef float floatx4 __attribute__((ext_vector_type(4)));

__device__ __forceinline__ void write_slab(float* __restrict__ slab, const float* vals,
                                           int m0, int lk, int lrow) {
#pragma unroll
    for (int nb = 0; nb < 4; ++nb)
#pragma unroll
        for (int r = 0; r < 4; ++r)
            slab[(m0 + lk * 4 + r) * 64 + nb * 16 + lrow] = vals[nb * 4 + r];
}

// ---------------- Kernel 1: fused cumsum + H1 build + in-register combines ---------
// grid = 16 bh * 2 halves; 256 threads = 4 waves (wave owns d-strip m0=16w).
__global__ __launch_bounds__(256) void prep_kernel(
    const float* __restrict__ g, const float* __restrict__ k,
    const float* __restrict__ v, float* __restrict__ cs,
    float* __restrict__ H) {
    const int bh = blockIdx.x >> 1;
    const int halfsel = blockIdx.x & 1;
    const int b = bh >> 3, h = bh & 7;
    const int tid = threadIdx.x;
    const int lane = tid & 63, wave = tid >> 6;
    const int m0 = wave * 16;
    const int lrow = lane & 15, lk = lane >> 4;

    __shared__ float csS[TT];
    __shared__ float part[256];
    __shared__ bf16 Kt[RT * LSTR];   // Kt[p][j] = exp(E_c - cs_j) * k_j[p]
    __shared__ bf16 Vt[RT * LSTR];   // Vt[d][j] = v_j[d]

    // ---- full scan of g[b,:,h] (each block does the whole row: 4 KB, keeps halves consistent)
    {
        float v0[4];
        float s = 0.f;
#pragma unroll
        for (int u = 0; u < 4; ++u) {
            s += g[(b * TT + (tid * 4 + u)) * HH + h];
            v0[u] = s;
        }
        part[tid] = s;
        __syncthreads();
        float x = s;
        for (int off = 1; off < 256; off <<= 1) {
            float y = (tid >= off) ? part[tid - off] : 0.f;
            __syncthreads();
            x += y;
            part[tid] = x;
            __syncthreads();
        }
        const float excl = x - s;
#pragma unroll
        for (int u = 0; u < 4; ++u) csS[tid * 4 + u] = excl + v0[u];
        if ((tid >> 7) == halfsel) {   // write our half of global cs
#pragma unroll
            for (int u = 0; u < 4; ++u) cs[bh * TT + tid * 4 + u] = excl + v0[u];
        }
    }

    float h2acc[16], h4acc[16], h8acc[16];
#pragma unroll
    for (int u = 0; u < 16; ++u) { h2acc[u] = 0.f; h4acc[u] = 0.f; h8acc[u] = 0.f; }

    for (int tt = 0; tt < 8; ++tt) {
        const int t8 = halfsel * 8 + tt;
        const int c0g = t8 * 64;
        __syncthreads();   // Kt/Vt reuse + csS visible (first iter)
        // ---- stage weighted K^T and V^T ----
        {
            const int jp = tid >> 3, p0 = (tid & 7) * 8;
            const int j0 = c0g + 2 * jp;
            const float Ec = csS[c0g + 63];
            const float w0 = __expf(Ec - csS[j0]);
            const float w1 = __expf(Ec - csS[j0 + 1]);
            const float* kp0 = k + ((size_t)((b * TT + j0) * HH) + h) * DD + p0;
            const float* kp1 = kp0 + HH * DD;
            const float* vp0 = v + ((size_t)((b * TT + j0) * HH) + h) * DD + p0;
            const float* vp1 = vp0 + HH * DD;
            float4 ka0 = *(const float4*)kp0, ka1 = *(const float4*)(kp0 + 4);
            float4 kb0 = *(const float4*)kp1, kb1 = *(const float4*)(kp1 + 4);
            float4 va0 = *(const float4*)vp0, va1 = *(const float4*)(vp0 + 4);
            float4 vb0 = *(const float4*)vp1, vb1 = *(const float4*)(vp1 + 4);
            float kr0[8] = {ka0.x, ka0.y, ka0.z, ka0.w, ka1.x, ka1.y, ka1.z, ka1.w};
            float kr1[8] = {kb0.x, kb0.y, kb0.z, kb0.w, kb1.x, kb1.y, kb1.z, kb1.w};
            float vr0[8] = {va0.x, va0.y, va0.z, va0.w, va1.x, va1.y, va1.z, va1.w};
            float vr1[8] = {vb0.x, vb0.y, vb0.z, vb0.w, vb1.x, vb1.y, vb1.z, vb1.w};
#pragma unroll
            for (int i2 = 0; i2 < 8; ++i2) {
                bf16x2 kk = {(bf16)(kr0[i2] * w0), (bf16)(kr1[i2] * w1)};
                *(bf16x2*)&Kt[(p0 + i2) * LSTR + 2 * jp] = kk;
                bf16x2 vv = {(bf16)vr0[i2], (bf16)vr1[i2]};
                *(bf16x2*)&Vt[(p0 + i2) * LSTR + 2 * jp] = vv;
            }
        }
        __syncthreads();

        // ---- H1 = V^T * (wK)  : C[d][p] ----
        bf16x8 a0 = *(bf16x8*)&Vt[(m0 + lrow) * LSTR + lk * 8];
        bf16x8 a1 = *(bf16x8*)&Vt[(m0 + lrow) * LSTR + 32 + lk * 8];
        float Hc[16];
#pragma unroll
        for (int nb = 0; nb < 4; ++nb) {
            bf16x8 b0 = *(bf16x8*)&Kt[(nb * 16 + lrow) * LSTR + lk * 8];
            bf16x8 b1 = *(bf16x8*)&Kt[(nb * 16 + lrow) * LSTR + 32 + lk * 8];
            floatx4 acc = {0.f, 0.f, 0.f, 0.f};
            acc = __builtin_amdgcn_mfma_f32_16x16x32_bf16(a0, b0, acc, 0, 0, 0);
            acc = __builtin_amdgcn_mfma_f32_16x16x32_bf16(a1, b1, acc, 0, 0, 0);
#pragma unroll
            for (int r = 0; r < 4; ++r) Hc[nb * 4 + r] = acc[r];
        }

        // ---- running combines (anchor rescaled to current tile end) ----
        const float decay = (t8 > 0) ? __expf(csS[c0g + 63] - csS[c0g - 1]) : 1.f;
        if ((t8 & 2) == 0) {           // H2 window {4m, 4m+1}
            if ((t8 & 3) == 0) {
#pragma unroll
                for (int u = 0; u < 16; ++u) h2acc[u] = Hc[u];
            } else {
#pragma unroll
                for (int u = 0; u < 16; ++u) h2acc[u] = h2acc[u] * decay + Hc[u];
                write_slab(H + (size_t)(bh * NSLOT + 16 + (t8 >> 2)) * SLAB, h2acc, m0, lk, lrow);
            }
        }
        if ((t8 & 4) == 0) {           // H4 window {8m..8m+3}
            if ((t8 & 7) == 0) {
#pragma unroll
                for (int u = 0; u < 16; ++u) h4acc[u] = Hc[u];
            } else {
#pragma unroll
                for (int u = 0; u < 16; ++u) h4acc[u] = h4acc[u] * decay + Hc[u];
            }
            if ((t8 & 7) == 3)
                write_slab(H + (size_t)(bh * NSLOT + 20 + (t8 >> 3)) * SLAB, h4acc, m0, lk, lrow);
        }
        if (halfsel == 0) {            // H8 window {0..7}
            if (t8 == 0) {
#pragma unroll
                for (int u = 0; u < 16; ++u) h8acc[u] = Hc[u];
            } else {
#pragma unroll
                for (int u = 0; u < 16; ++u) h8acc[u] = h8acc[u] * decay + Hc[u];
            }
            if (t8 == 7)
                write_slab(H + (size_t)(bh * NSLOT + 22) * SLAB, h8acc, m0, lk, lrow);
        }
        if ((t8 & 1) == 0)             // only even H1 slots are consumed (slot rt-1, rt odd)
            write_slab(H + (size_t)(bh * NSLOT + t8) * SLAB, Hc, m0, lk, lrow);
    }
}

// ---------------- Kernel 2: output pass, one block per (bh, rt) --------------------
// 256 threads = 4 waves (wave owns 16-row strip). Single barrier: stage everything,
// then unbroken MFMA stream (diag levels 0..6 direct + levels 7..10 via slabs).
__global__ __launch_bounds__(256) void out_kernel(
    const float* __restrict__ q, const float* __restrict__ k,
    const float* __restrict__ v, const float* __restrict__ L,
    const float* __restrict__ cs, const float* __restrict__ H,
    float* __restrict__ out) {
    const int blk = blockIdx.x;
    const int rt = blk & 15;
    const int bh = blk >> 4;
    const int b = bh >> 3, h = bh & 7;
    const int tid = threadIdx.x;
    const int lane = tid & 63, wave = tid >> 6;
    const int m0 = wave * 16;
    const int lrow = lane & 15, lk = lane >> 4;

    __shared__ bf16 Qs[64 * LSTR];     // aliased as P after Q frags move to registers
    __shared__ bf16 Ks[64 * LSTR];
    __shared__ bf16 Vt[64 * LSTR];
    __shared__ bf16 Hs[4 * 64 * LSTR];
    __shared__ float Lsh[7 * 64];
    __shared__ float Lw4[4 * 64];
    __shared__ float cs64[64];
    __shared__ float ErefS[4];

    // ---- stage Q, K ----
    {
        const int il = tid >> 2, d0 = (tid & 3) * 16;
        const float* qp = q + ((size_t)((b * TT + rt * RT + il) * HH) + h) * DD + d0;
        const float* kp = k + ((size_t)((b * TT + rt * RT + il) * HH) + h) * DD + d0;
#pragma unroll
        for (int u = 0; u < 16; u += 4) {
            float4 f = *(const float4*)(qp + u);
            bf16x4 w4 = {(bf16)f.x, (bf16)f.y, (bf16)f.z, (bf16)f.w};
            *(bf16x4*)&Qs[il * LSTR + d0 + u] = w4;
            float4 fk = *(const float4*)(kp + u);
            bf16x4 wk = {(bf16)fk.x, (bf16)fk.y, (bf16)fk.z, (bf16)fk.w};
            *(bf16x4*)&Ks[il * LSTR + d0 + u] = wk;
        }
    }
    // ---- stage V transposed ----
    {
        const int jp = tid >> 3, p0 = (tid & 7) * 8;
        const float* vp0 = v + ((size_t)((b * TT + rt * RT + 2 * jp) * HH) + h) * DD + p0;
        const float* vp1 = vp0 + HH * DD;
        float4 a0 = *(const float4*)(vp0);
        float4 a1 = *(const float4*)(vp0 + 4);
        float4 b0 = *(const float4*)(vp1);
        float4 b1 = *(const float4*)(vp1 + 4);
        float r0[8] = {a0.x, a0.y, a0.z, a0.w, a1.x, a1.y, a1.z, a1.w};
        float r1[8] = {b0.x, b0.y, b0.z, b0.w, b1.x, b1.y, b1.z, b1.w};
#pragma unroll
        for (int i2 = 0; i2 < 8; ++i2) {
            bf16x2 w2 = {(bf16)r0[i2], (bf16)r1[i2]};
            *(bf16x2*)&Vt[(p0 + i2) * LSTR + 2 * jp] = w2;
        }
    }
    // ---- stage cs, L (diag levels + hier levels), Eref, slabs ----
    if (tid < 64) cs64[tid] = cs[bh * TT + rt * RT + tid];
    for (int u = tid; u < 7 * 64; u += 256)
        Lsh[u] = L[((size_t)bh * NLEV + (u >> 6)) * TT + rt * RT + (u & 63)];
    Lw4[tid] = L[((size_t)bh * NLEV + 7 + (tid >> 6)) * TT + rt * RT + (tid & 63)];
    if (tid < 4) {
        const int s = tid;
        float e = 0.f;
        if ((rt >> s) & 1) {
            const int reft = (s == 0) ? rt - 1 : (s == 1) ? (rt & ~1) - 1
                           : (s == 2) ? (rt & ~3) - 1 : 7;
            e = cs[bh * TT + reft * RT + 63];
        }
        ErefS[s] = e;
    }
    {
        const int row = tid >> 2, q4 = tid & 3;
#pragma unroll
        for (int s = 0; s < 4; ++s) {
            if (!((rt >> s) & 1)) continue;
            const int slot = (s == 0) ? rt - 1 : (s == 1) ? 16 + (rt >> 2)
                           : (s == 2) ? 20 + (rt >> 3) : 22;
            const float* hp = H + (size_t)(bh * NSLOT + slot) * SLAB + row * 64 + q4 * 16;
#pragma unroll
            for (int u = 0; u < 16; u += 4) {
                float4 f = *(const float4*)(hp + u);
                bf16x4 w4 = {(bf16)f.x, (bf16)f.y, (bf16)f.z, (bf16)f.w};
                *(bf16x4*)&Hs[(s * 64 + row) * LSTR + q4 * 16 + u] = w4;
            }
        }
    }
    __syncthreads();

    bf16x8 qa0 = *(bf16x8*)&Qs[(m0 + lrow) * LSTR + lk * 8];
    bf16x8 qa1 = *(bf16x8*)&Qs[(m0 + lrow) * LSTR + 32 + lk * 8];
    float csr[4];
#pragma unroll
    for (int r = 0; r < 4; ++r) csr[r] = cs64[m0 + lk * 4 + r];

    // ---- diagonal: S = Q K^T ----
    floatx4 sacc[4];
#pragma unroll
    for (int nb = 0; nb < 4; ++nb) {
        bf16x8 b0 = *(bf16x8*)&Ks[(nb * 16 + lrow) * LSTR + lk * 8];
        bf16x8 b1 = *(bf16x8*)&Ks[(nb * 16 + lrow) * LSTR + 32 + lk * 8];
        floatx4 acc = {0.f, 0.f, 0.f, 0.f};
        acc = __builtin_amdgcn_mfma_f32_16x16x32_bf16(qa0, b0, acc, 0, 0, 0);
        acc = __builtin_amdgcn_mfma_f32_16x16x32_bf16(qa1, b1, acc, 0, 0, 0);
        sacc[nb] = acc;
    }
    // ---- weight levels 0..6 -> P (into Qs, own-wave strip: no barrier needed) ----
#pragma unroll
    for (int nb = 0; nb < 4; ++nb) {
        const int jl = nb * 16 + lrow;
        const float csj = cs64[jl];
#pragma unroll
        for (int r = 0; r < 4; ++r) {
            const int rowl = m0 + lk * 4 + r;
            float wgt = 0.f;
            if (jl <= rowl) {
                const int x = rowl ^ jl;
                const int lev0 = x ? (32 - __clz(x)) : 0;
                wgt = __expf(csr[r] - csj) * Lsh[lev0 * 64 + rowl];
            }
            Qs[rowl * LSTR + jl] = (bf16)(sacc[nb][r] * wgt);
        }
    }
    bf16x8 pa0 = *(bf16x8*)&Qs[(m0 + lrow) * LSTR + lk * 8];
    bf16x8 pa1 = *(bf16x8*)&Qs[(m0 + lrow) * LSTR + 32 + lk * 8];
    floatx4 O[4];
#pragma unroll
    for (int nb = 0; nb < 4; ++nb) {
        bf16x8 b0 = *(bf16x8*)&Vt[(nb * 16 + lrow) * LSTR + lk * 8];
        bf16x8 b1 = *(bf16x8*)&Vt[(nb * 16 + lrow) * LSTR + 32 + lk * 8];
        floatx4 acc = {0.f, 0.f, 0.f, 0.f};
        acc = __builtin_amdgcn_mfma_f32_16x16x32_bf16(pa0, b0, acc, 0, 0, 0);
        acc = __builtin_amdgcn_mfma_f32_16x16x32_bf16(pa1, b1, acc, 0, 0, 0);
        O[nb] = acc;
    }

    // ---- hierarchical levels 7..10 via staged slabs ----
#pragma unroll
    for (int s = 0; s < 4; ++s) {
        if (!((rt >> s) & 1)) continue;
        float wr[4];
#pragma unroll
        for (int r = 0; r < 4; ++r)
            wr[r] = Lw4[s * 64 + m0 + lk * 4 + r] * __expf(csr[r] - ErefS[s]);
#pragma unroll
        for (int nb = 0; nb < 4; ++nb) {
            bf16x8 b0 = *(bf16x8*)&Hs[(s * 64 + nb * 16 + lrow) * LSTR + lk * 8];
            bf16x8 b1 = *(bf16x8*)&Hs[(s * 64 + nb * 16 + lrow) * LSTR + 32 + lk * 8];
            floatx4 acc = {0.f, 0.f, 0.f, 0.f};
            acc = __builtin_amdgcn_mfma_f32_16x16x32_bf16(qa0, b0, acc, 0, 0, 0);
            acc = __builtin_amdgcn_mfma_f32_16x16x32_bf16(qa1, b1, acc, 0, 0, 0);
#pragma unroll
            for (int r = 0; r < 4; ++r) O[nb][r] += wr[r] * acc[r];
        }
    }

    // ---- epilogue ----
#pragma unroll
    for (int r = 0; r < 4; ++r) {
        const int ig = rt * RT + m0 + lk * 4 + r;
        float* op = out + ((size_t)((b * TT + ig) * HH) + h) * DD;
#pragma unroll
        for (int nb = 0; nb < 4; ++nb)
            op[nb * 16 + lrow] = O[nb][r];
    }
}

extern "C" void kernel_launch(void* const* d_in, const int* in_sizes, int n_in,
                              void* d_out, int out_size, void* d_ws, size_t ws_size,
                              hipStream_t stream) {
    const float* q = (const float*)d_in[0];
    const float* k = (const float*)d_in[1];
    const float* v = (const float*)d_in[2];
    const float* g = (const float*)d_in[3];
    const float* L = (const float*)d_in[4];
    float* out = (float*)d_out;
    float* cs = (float*)d_ws;                    // 16*1024 floats
    float* H = (float*)d_ws + 16384;             // 16*23*4096 floats (~6 MB)

    prep_kernel<<<BD * HH * 2, 256, 0, stream>>>(g, k, v, cs, H);
    out_kernel<<<BD * HH * NT, 256, 0, stream>>>(q, k, v, L, cs, H, out);
}

// Round 6
// 89.110 us; speedup vs baseline: 1.1746x; 1.0183x over previous
//
#include <hip/hip_runtime.h>
#include <hip/hip_bf16.h>

#define BD 2
#define TT 1024
#define HH 8
#define DD 64
#define NLEV 11
#define RT 64
#define NT 16
#define LSTR 72            // LDS row stride (bf16): 144B, proven layout from R1-R5

typedef __bf16 bf16;
typedef bf16 bf16x2 __attribute__((ext_vector_type(2)));
typedef bf16 bf16x4 __attribute__((ext_vector_type(4)));
typedef bf16 bf16x8 __attribute__((ext_vector_type(8)));
typedef float floatx4 __attribute__((ext_vector_type(4)));

struct Pref {                // per-thread prefetch: K rows 2jp,2jp+1 dims p0..p0+7; same for V
    float4 kA0, kA1, kB0, kB1, vA0, vA1, vB0, vB1;
};

__device__ __forceinline__ void prefetch_tile(const float* __restrict__ k,
                                              const float* __restrict__ v,
                                              int b, int h, int tile, int jp, int p0,
                                              Pref& P) {
    const int j0 = tile * RT + 2 * jp;
    const float* kp0 = k + ((size_t)((b * TT + j0) * HH) + h) * DD + p0;
    const float* vp0 = v + ((size_t)((b * TT + j0) * HH) + h) * DD + p0;
    P.kA0 = *(const float4*)kp0;            P.kA1 = *(const float4*)(kp0 + 4);
    P.kB0 = *(const float4*)(kp0 + HH*DD);  P.kB1 = *(const float4*)(kp0 + HH*DD + 4);
    P.vA0 = *(const float4*)vp0;            P.vA1 = *(const float4*)(vp0 + 4);
    P.vB0 = *(const float4*)(vp0 + HH*DD);  P.vB1 = *(const float4*)(vp0 + HH*DD + 4);
}

// One fused kernel: block (bh, rt). Streams its causal prefix tiles [0, rt) to build
// the <=4 binary-range KV summaries in registers (snapshots -> LDS), then does the
// diagonal tile (levels 0..6 per-element) + hierarchical Q*Htilde blends (levels 7..10).
__global__ __launch_bounds__(256) void hattn_fused_kernel(
    const float* __restrict__ q, const float* __restrict__ k,
    const float* __restrict__ v, const float* __restrict__ g,
    const float* __restrict__ L, float* __restrict__ out) {
    const int blk = blockIdx.x;
    const int rt = blk & 15;
    const int bh = blk >> 4;
    const int b = bh >> 3, h = bh & 7;
    const int tid = threadIdx.x;
    const int lane = tid & 63, wave = tid >> 6;
    const int m0 = wave * 16;
    const int lrow = lane & 15, lk = lane >> 4;
    const int jp = tid >> 3;          // staging: rows 2jp, 2jp+1
    const int p0 = (tid & 7) * 8;     // staging: dims p0..p0+7

    __shared__ float csS[TT];
    __shared__ float waveTot[4];
    __shared__ bf16 Qs[RT * LSTR];    // aliased as P scratch after frags extracted
    __shared__ bf16 Kt[RT * LSTR];    // stream: weighted K^T [p][j]; diag: K row-major [j][d]
    __shared__ bf16 Vt[RT * LSTR];    // V^T [vdim][j]
    __shared__ bf16 Hs[4 * RT * LSTR];// snapshots: Hs[s][vdim][kdim]
    __shared__ float Lsh[7 * RT];
    __shared__ float Lw4[4 * RT];

    Pref P;
    prefetch_tile(k, v, b, h, 0, jp, p0, P);   // tile 0 (stream start, or diag if rt==0)

    // ---- cumsum of g[b,:,h] via wave-shuffle scan (redundant per block, cheap) ----
    {
        float v4[4];
        float s = 0.f;
#pragma unroll
        for (int u = 0; u < 4; ++u) {
            s += g[(b * TT + (tid * 4 + u)) * HH + h];
            v4[u] = s;
        }
        const float tot = s;
#pragma unroll
        for (int off = 1; off < 64; off <<= 1) {
            const float y = __shfl_up(s, off, 64);
            if (lane >= off) s += y;
        }
        if (lane == 63) waveTot[wave] = s;
        __syncthreads();
        float woff = 0.f;
        for (int w = 0; w < 4; ++w)
            if (w < wave) woff += waveTot[w];
        const float excl = woff + s - tot;
#pragma unroll
        for (int u = 0; u < 4; ++u) csS[tid * 4 + u] = excl + v4[u];
    }

    // ---- stage Q tile + L rows (concurrent with csS writes; one barrier below) ----
    {
        const int il = tid >> 2, d0 = (tid & 3) * 16;
        const float* qp = q + ((size_t)((b * TT + rt * RT + il) * HH) + h) * DD + d0;
#pragma unroll
        for (int u = 0; u < 16; u += 4) {
            float4 f = *(const float4*)(qp + u);
            bf16x4 w4 = {(bf16)f.x, (bf16)f.y, (bf16)f.z, (bf16)f.w};
            *(bf16x4*)&Qs[il * LSTR + d0 + u] = w4;
        }
    }
    for (int u = tid; u < 7 * RT; u += 256)
        Lsh[u] = L[((size_t)bh * NLEV + (u >> 6)) * TT + rt * RT + (u & 63)];
    Lw4[tid] = L[((size_t)bh * NLEV + 7 + (tid >> 6)) * TT + rt * RT + (tid & 63)];
    __syncthreads();   // csS, Qs visible

    const bf16x8 qa0 = *(bf16x8*)&Qs[(m0 + lrow) * LSTR + lk * 8];
    const bf16x8 qa1 = *(bf16x8*)&Qs[(m0 + lrow) * LSTR + 32 + lk * 8];
    float csr[4];
#pragma unroll
    for (int r = 0; r < 4; ++r) csr[r] = csS[rt * RT + m0 + lk * 4 + r];

    // ---- stream prefix tiles: binary ranges (consecutive), snapshot per set bit ----
    float eref[4] = {0.f, 0.f, 0.f, 0.f};
    int ct = 0;
#pragma unroll
    for (int s = 3; s >= 0; --s) {
        if (!((rt >> s) & 1)) continue;
        const int len = 1 << s;
        floatx4 acc[4];
#pragma unroll
        for (int nb = 0; nb < 4; ++nb) acc[nb] = (floatx4){0.f, 0.f, 0.f, 0.f};
        for (int ii = 0; ii < len; ++ii, ++ct) {
            __syncthreads();   // prior Kt/Vt readers done
            // stage weighted K^T + V^T from prefetch regs
            {
                const int j0 = ct * RT + 2 * jp;
                const float E = csS[ct * RT + 63];
                const float w0 = __expf(E - csS[j0]);
                const float w1 = __expf(E - csS[j0 + 1]);
                float kr0[8] = {P.kA0.x, P.kA0.y, P.kA0.z, P.kA0.w, P.kA1.x, P.kA1.y, P.kA1.z, P.kA1.w};
                float kr1[8] = {P.kB0.x, P.kB0.y, P.kB0.z, P.kB0.w, P.kB1.x, P.kB1.y, P.kB1.z, P.kB1.w};
                float vr0[8] = {P.vA0.x, P.vA0.y, P.vA0.z, P.vA0.w, P.vA1.x, P.vA1.y, P.vA1.z, P.vA1.w};
                float vr1[8] = {P.vB0.x, P.vB0.y, P.vB0.z, P.vB0.w, P.vB1.x, P.vB1.y, P.vB1.z, P.vB1.w};
#pragma unroll
                for (int i2 = 0; i2 < 8; ++i2) {
                    bf16x2 kk = {(bf16)(kr0[i2] * w0), (bf16)(kr1[i2] * w1)};
                    *(bf16x2*)&Kt[(p0 + i2) * LSTR + 2 * jp] = kk;
                    bf16x2 vv = {(bf16)vr0[i2], (bf16)vr1[i2]};
                    *(bf16x2*)&Vt[(p0 + i2) * LSTR + 2 * jp] = vv;
                }
            }
            __syncthreads();
            const int nxt = (ct + 1 < rt) ? (ct + 1) : rt;   // next stream tile, or diag
            prefetch_tile(k, v, b, h, nxt, jp, p0, P);
            if (ii > 0) {   // rescale anchor to current tile end
                const float d = __expf(csS[ct * RT + 63] - csS[ct * RT - 1]);
#pragma unroll
                for (int nb = 0; nb < 4; ++nb)
#pragma unroll
                    for (int r = 0; r < 4; ++r) acc[nb][r] *= d;
            }
            const bf16x8 a0 = *(bf16x8*)&Vt[(m0 + lrow) * LSTR + lk * 8];
            const bf16x8 a1 = *(bf16x8*)&Vt[(m0 + lrow) * LSTR + 32 + lk * 8];
#pragma unroll
            for (int nb = 0; nb < 4; ++nb) {
                bf16x8 b0 = *(bf16x8*)&Kt[(nb * 16 + lrow) * LSTR + lk * 8];
                bf16x8 b1 = *(bf16x8*)&Kt[(nb * 16 + lrow) * LSTR + 32 + lk * 8];
                acc[nb] = __builtin_amdgcn_mfma_f32_16x16x32_bf16(a0, b0, acc[nb], 0, 0, 0);
                acc[nb] = __builtin_amdgcn_mfma_f32_16x16x32_bf16(a1, b1, acc[nb], 0, 0, 0);
            }
        }
        eref[s] = csS[ct * RT - 1];   // range-end anchor
        // snapshot to Hs[s] (own d-strip rows; visibility via next barrier)
#pragma unroll
        for (int nb = 0; nb < 4; ++nb)
#pragma unroll
            for (int r = 0; r < 4; ++r)
                Hs[(s * RT + m0 + lk * 4 + r) * LSTR + nb * 16 + lrow] = (bf16)acc[nb][r];
    }

    // ---- diagonal tile staging (K row-major, V^T) from prefetch regs ----
    __syncthreads();   // snapshots visible to all; Kt/Vt free
    {
        bf16x4 w0 = {(bf16)P.kA0.x, (bf16)P.kA0.y, (bf16)P.kA0.z, (bf16)P.kA0.w};
        bf16x4 w1 = {(bf16)P.kA1.x, (bf16)P.kA1.y, (bf16)P.kA1.z, (bf16)P.kA1.w};
        bf16x4 w2 = {(bf16)P.kB0.x, (bf16)P.kB0.y, (bf16)P.kB0.z, (bf16)P.kB0.w};
        bf16x4 w3 = {(bf16)P.kB1.x, (bf16)P.kB1.y, (bf16)P.kB1.z, (bf16)P.kB1.w};
        *(bf16x4*)&Kt[(2 * jp) * LSTR + p0] = w0;
        *(bf16x4*)&Kt[(2 * jp) * LSTR + p0 + 4] = w1;
        *(bf16x4*)&Kt[(2 * jp + 1) * LSTR + p0] = w2;
        *(bf16x4*)&Kt[(2 * jp + 1) * LSTR + p0 + 4] = w3;
        float vr0[8] = {P.vA0.x, P.vA0.y, P.vA0.z, P.vA0.w, P.vA1.x, P.vA1.y, P.vA1.z, P.vA1.w};
        float vr1[8] = {P.vB0.x, P.vB0.y, P.vB0.z, P.vB0.w, P.vB1.x, P.vB1.y, P.vB1.z, P.vB1.w};
#pragma unroll
        for (int i2 = 0; i2 < 8; ++i2) {
            bf16x2 vv = {(bf16)vr0[i2], (bf16)vr1[i2]};
            *(bf16x2*)&Vt[(p0 + i2) * LSTR + 2 * jp] = vv;
        }
    }
    __syncthreads();

    // ---- diagonal: S = Q K^T, per-element weight (levels 0..6), P V ----
    floatx4 sacc[4];
#pragma unroll
    for (int nb = 0; nb < 4; ++nb) {
        bf16x8 b0 = *(bf16x8*)&Kt[(nb * 16 + lrow) * LSTR + lk * 8];
        bf16x8 b1 = *(bf16x8*)&Kt[(nb * 16 + lrow) * LSTR + 32 + lk * 8];
        floatx4 a = {0.f, 0.f, 0.f, 0.f};
        a = __builtin_amdgcn_mfma_f32_16x16x32_bf16(qa0, b0, a, 0, 0, 0);
        a = __builtin_amdgcn_mfma_f32_16x16x32_bf16(qa1, b1, a, 0, 0, 0);
        sacc[nb] = a;
    }
#pragma unroll
    for (int nb = 0; nb < 4; ++nb) {
        const int jl = nb * 16 + lrow;
        const float csj = csS[rt * RT + jl];
#pragma unroll
        for (int r = 0; r < 4; ++r) {
            const int rowl = m0 + lk * 4 + r;
            float wgt = 0.f;
            if (jl <= rowl) {
                const int x = rowl ^ jl;
                const int lev0 = x ? (32 - __clz(x)) : 0;
                wgt = __expf(csr[r] - csj) * Lsh[lev0 * RT + rowl];
            }
            Qs[rowl * LSTR + jl] = (bf16)(sacc[nb][r] * wgt);
        }
    }
    // own-wave strip: in-order LDS, no barrier
    const bf16x8 pa0 = *(bf16x8*)&Qs[(m0 + lrow) * LSTR + lk * 8];
    const bf16x8 pa1 = *(bf16x8*)&Qs[(m0 + lrow) * LSTR + 32 + lk * 8];
    floatx4 O[4];
#pragma unroll
    for (int nb = 0; nb < 4; ++nb) {
        bf16x8 b0 = *(bf16x8*)&Vt[(nb * 16 + lrow) * LSTR + lk * 8];
        bf16x8 b1 = *(bf16x8*)&Vt[(nb * 16 + lrow) * LSTR + 32 + lk * 8];
        floatx4 a = {0.f, 0.f, 0.f, 0.f};
        a = __builtin_amdgcn_mfma_f32_16x16x32_bf16(pa0, b0, a, 0, 0, 0);
        a = __builtin_amdgcn_mfma_f32_16x16x32_bf16(pa1, b1, a, 0, 0, 0);
        O[nb] = a;
    }

    // ---- hierarchical levels 7..10 from Hs snapshots ----
#pragma unroll
    for (int s = 3; s >= 0; --s) {
        if (!((rt >> s) & 1)) continue;
        float wr[4];
#pragma unroll
        for (int r = 0; r < 4; ++r)
            wr[r] = Lw4[s * RT + m0 + lk * 4 + r] * __expf(csr[r] - eref[s]);
#pragma unroll
        for (int nb = 0; nb < 4; ++nb) {
            bf16x8 b0 = *(bf16x8*)&Hs[(s * RT + nb * 16 + lrow) * LSTR + lk * 8];
            bf16x8 b1 = *(bf16x8*)&Hs[(s * RT + nb * 16 + lrow) * LSTR + 32 + lk * 8];
            floatx4 a = {0.f, 0.f, 0.f, 0.f};
            a = __builtin_amdgcn_mfma_f32_16x16x32_bf16(qa0, b0, a, 0, 0, 0);
            a = __builtin_amdgcn_mfma_f32_16x16x32_bf16(qa1, b1, a, 0, 0, 0);
#pragma unroll
            for (int r = 0; r < 4; ++r) O[nb][r] += wr[r] * a[r];
        }
    }

    // ---- epilogue ----
#pragma unroll
    for (int r = 0; r < 4; ++r) {
        const int ig = rt * RT + m0 + lk * 4 + r;
        float* op = out + ((size_t)((b * TT + ig) * HH) + h) * DD;
#pragma unroll
        for (int nb = 0; nb < 4; ++nb)
            op[nb * 16 + lrow] = O[nb][r];
    }
}

extern "C" void kernel_launch(void* const* d_in, const int* in_sizes, int n_in,
                              void* d_out, int out_size, void* d_ws, size_t ws_size,
                              hipStream_t stream) {
    const float* q = (const float*)d_in[0];
    const float* k = (const float*)d_in[1];
    const float* v = (const float*)d_in[2];
    const float* g = (const float*)d_in[3];
    const float* L = (const float*)d_in[4];
    float* out = (float*)d_out;

    hattn_fused_kernel<<<BD * HH * NT, 256, 0, stream>>>(q, k, v, g, L, out);
}

// Round 7
// 87.023 us; speedup vs baseline: 1.2028x; 1.0240x over previous
//
#include <hip/hip_runtime.h>
#include <hip/hip_bf16.h>

#define BD 2
#define TT 1024
#define HH 8
#define DD 64
#define NLEV 11
#define RT 64
#define NT 16
#define LSTR 72            // LDS row stride (bf16): 144B, proven layout R1-R6
#define SSTR 65            // fp32 scratch stride

typedef __bf16 bf16;
typedef bf16 bf16x2 __attribute__((ext_vector_type(2)));
typedef bf16 bf16x4 __attribute__((ext_vector_type(4)));
typedef bf16 bf16x8 __attribute__((ext_vector_type(8)));
typedef float floatx4 __attribute__((ext_vector_type(4)));

struct Pref {                // per-thread prefetch: K rows 2jp,2jp+1 dims p0..p0+7; same for V
    float4 kA0, kA1, kB0, kB1, vA0, vA1, vB0, vB1;
};

__device__ __forceinline__ void prefetch_tile(const float* __restrict__ k,
                                              const float* __restrict__ v,
                                              int b, int h, int tile, int jp, int p0,
                                              Pref& P) {
    const int j0 = tile * RT + 2 * jp;
    const float* kp0 = k + ((size_t)((b * TT + j0) * HH) + h) * DD + p0;
    const float* vp0 = v + ((size_t)((b * TT + j0) * HH) + h) * DD + p0;
    P.kA0 = *(const float4*)kp0;            P.kA1 = *(const float4*)(kp0 + 4);
    P.kB0 = *(const float4*)(kp0 + HH*DD);  P.kB1 = *(const float4*)(kp0 + HH*DD + 4);
    P.vA0 = *(const float4*)vp0;            P.vA1 = *(const float4*)(vp0 + 4);
    P.vB0 = *(const float4*)(vp0 + HH*DD);  P.vB1 = *(const float4*)(vp0 + HH*DD + 4);
}

// One fused kernel, block (bh, rt), 512 threads = 2 tile-groups x 4 waves.
// Group g streams tiles at parity g within each binary range of [0, rt); partial
// range summaries combine through fp32 LDS scratch. Diagonal tile: col-halves
// split across groups. Levels 7..10 via Q*Htilde blends.
__global__ __launch_bounds__(512) void hattn_fused_kernel(
    const float* __restrict__ q, const float* __restrict__ k,
    const float* __restrict__ v, const float* __restrict__ g,
    const float* __restrict__ L, float* __restrict__ out) {
    const int blk = blockIdx.x;
    const int rt = blk & 15;
    const int bh = blk >> 4;
    const int b = bh >> 3, h = bh & 7;
    const int tid = threadIdx.x;       // 0..511
    const int lane = tid & 63;
    const int wave = tid >> 6;         // 0..7
    const int grp = wave >> 2;         // tile-parity group
    const int mw = wave & 3;           // strip within group
    const int m0 = mw * 16;
    const int lrow = lane & 15, lk = lane >> 4;
    const int gtid = tid & 255;        // staging id within group
    const int jp = gtid >> 3;          // rows 2jp, 2jp+1
    const int p0 = (gtid & 7) * 8;     // dims p0..p0+7

    __shared__ float csS[TT];
    __shared__ float waveTot[8];
    __shared__ bf16 Qs[RT * LSTR];     // Q, later aliased as P
    __shared__ bf16 Kt[2][RT * LSTR];  // per-group staging
    __shared__ bf16 Vt[2][RT * LSTR];
    __shared__ bf16 Hs[4 * RT * LSTR]; // range summaries (bf16) per set bit s
    __shared__ float scr[RT * SSTR];   // fp32 combine scratch
    __shared__ float Lsh[7 * RT];
    __shared__ float Lw4[4 * RT];

    // ---- per-group tile list (ranges s=3..0, parity tiles ascending, then diag) ----
    int list[9];
    int nlist = 0;
    {
        int t0 = 0;
        for (int s = 3; s >= 0; --s) {
            if (!((rt >> s) & 1)) continue;
            const int len = 1 << s;
            for (int u = grp; u < len; u += 2) list[nlist++] = t0 + u;
            t0 += len;
        }
        list[nlist++] = rt;            // diag tile
    }
    Pref P;
    prefetch_tile(k, v, b, h, list[0], jp, p0, P);
    int pidx = 0;

    // ---- cumsum of g[b,:,h]: wave scan + cross-wave offsets (2 elems/thread) ----
    {
        const float a0 = g[(b * TT + tid * 2) * HH + h];
        const float a1 = g[(b * TT + tid * 2 + 1) * HH + h];
        float s = a0 + a1;
        const float tot = s;
#pragma unroll
        for (int off = 1; off < 64; off <<= 1) {
            const float y = __shfl_up(s, off, 64);
            if (lane >= off) s += y;
        }
        if (lane == 63) waveTot[wave] = s;
        __syncthreads();
        float woff = 0.f;
        for (int w = 0; w < 8; ++w)
            if (w < wave) woff += waveTot[w];
        const float excl = woff + s - tot;
        csS[tid * 2] = excl + a0;
        csS[tid * 2 + 1] = excl + a0 + a1;
    }

    // ---- stage Q + L rows ----
    {
        const int il = tid >> 3, d0 = (tid & 7) * 8;
        const float* qp = q + ((size_t)((b * TT + rt * RT + il) * HH) + h) * DD + d0;
#pragma unroll
        for (int u = 0; u < 8; u += 4) {
            float4 f = *(const float4*)(qp + u);
            bf16x4 w4 = {(bf16)f.x, (bf16)f.y, (bf16)f.z, (bf16)f.w};
            *(bf16x4*)&Qs[il * LSTR + d0 + u] = w4;
        }
    }
    if (tid < 7 * RT) Lsh[tid] = L[((size_t)bh * NLEV + (tid >> 6)) * TT + rt * RT + (tid & 63)];
    if (tid < 4 * RT) Lw4[tid] = L[((size_t)bh * NLEV + 7 + (tid >> 6)) * TT + rt * RT + (tid & 63)];
    __syncthreads();   // csS, Qs, Lsh, Lw4 visible

    const bf16x8 qa0 = *(bf16x8*)&Qs[(m0 + lrow) * LSTR + lk * 8];
    const bf16x8 qa1 = *(bf16x8*)&Qs[(m0 + lrow) * LSTR + 32 + lk * 8];
    float csr[4];
#pragma unroll
    for (int r = 0; r < 4; ++r) csr[r] = csS[rt * RT + m0 + lk * 4 + r];

    // ---- stream ranges with parity-split tiles ----
    float eref4[4] = {0.f, 0.f, 0.f, 0.f};
    int t0 = 0;
#pragma unroll
    for (int s = 3; s >= 0; --s) {
        if (!((rt >> s) & 1)) continue;
        const int len = 1 << s;
        const int iters = (len >= 2) ? (len >> 1) : 1;
        floatx4 acc[4];
#pragma unroll
        for (int nb = 0; nb < 4; ++nb) acc[nb] = (floatx4){0.f, 0.f, 0.f, 0.f};
        float aprev = 0.f;
        bool any = false;
        for (int ii = 0; ii < iters; ++ii) {
            const int myoff = 2 * ii + grp;
            const bool valid = myoff < len;
            const int ct = t0 + myoff;
            const float E = valid ? csS[ct * RT + 63] : 0.f;
            __syncthreads();   // prev readers of Kt/Vt[grp] done; Hs of prev range visible
            if (valid) {
                const int j0 = ct * RT + 2 * jp;
                const float w0 = __expf(E - csS[j0]);
                const float w1 = __expf(E - csS[j0 + 1]);
                float kr0[8] = {P.kA0.x, P.kA0.y, P.kA0.z, P.kA0.w, P.kA1.x, P.kA1.y, P.kA1.z, P.kA1.w};
                float kr1[8] = {P.kB0.x, P.kB0.y, P.kB0.z, P.kB0.w, P.kB1.x, P.kB1.y, P.kB1.z, P.kB1.w};
                float vr0[8] = {P.vA0.x, P.vA0.y, P.vA0.z, P.vA0.w, P.vA1.x, P.vA1.y, P.vA1.z, P.vA1.w};
                float vr1[8] = {P.vB0.x, P.vB0.y, P.vB0.z, P.vB0.w, P.vB1.x, P.vB1.y, P.vB1.z, P.vB1.w};
#pragma unroll
                for (int i2 = 0; i2 < 8; ++i2) {
                    bf16x2 kk = {(bf16)(kr0[i2] * w0), (bf16)(kr1[i2] * w1)};
                    *(bf16x2*)&Kt[grp][(p0 + i2) * LSTR + 2 * jp] = kk;
                    bf16x2 vv = {(bf16)vr0[i2], (bf16)vr1[i2]};
                    *(bf16x2*)&Vt[grp][(p0 + i2) * LSTR + 2 * jp] = vv;
                }
                ++pidx;
                if (pidx < nlist) prefetch_tile(k, v, b, h, list[pidx], jp, p0, P);
            }
            __syncthreads();
            if (valid) {
                if (any) {
                    const float d = __expf(E - aprev);
#pragma unroll
                    for (int nb = 0; nb < 4; ++nb)
#pragma unroll
                        for (int r = 0; r < 4; ++r) acc[nb][r] *= d;
                }
                const bf16x8 a0 = *(bf16x8*)&Vt[grp][(m0 + lrow) * LSTR + lk * 8];
                const bf16x8 a1 = *(bf16x8*)&Vt[grp][(m0 + lrow) * LSTR + 32 + lk * 8];
#pragma unroll
                for (int nb = 0; nb < 4; ++nb) {
                    bf16x8 b0 = *(bf16x8*)&Kt[grp][(nb * 16 + lrow) * LSTR + lk * 8];
                    bf16x8 b1 = *(bf16x8*)&Kt[grp][(nb * 16 + lrow) * LSTR + 32 + lk * 8];
                    acc[nb] = __builtin_amdgcn_mfma_f32_16x16x32_bf16(a0, b0, acc[nb], 0, 0, 0);
                    acc[nb] = __builtin_amdgcn_mfma_f32_16x16x32_bf16(a1, b1, acc[nb], 0, 0, 0);
                }
                aprev = E;
                any = true;
            }
        }
        const float Eend = csS[(t0 + len) * RT - 1];
        eref4[s] = Eend;
        __syncthreads();   // MFMAs done; scr free for reuse
        if (grp == 1) {
            const float fac = any ? __expf(Eend - aprev) : 0.f;
#pragma unroll
            for (int nb = 0; nb < 4; ++nb)
#pragma unroll
                for (int r = 0; r < 4; ++r)
                    scr[(m0 + lk * 4 + r) * SSTR + nb * 16 + lrow] =
                        any ? acc[nb][r] * fac : 0.f;
        }
        __syncthreads();
        if (grp == 0) {
            const float fac = __expf(Eend - aprev);   // grp0 always has tiles
#pragma unroll
            for (int nb = 0; nb < 4; ++nb)
#pragma unroll
                for (int r = 0; r < 4; ++r)
                    Hs[(s * RT + m0 + lk * 4 + r) * LSTR + nb * 16 + lrow] =
                        (bf16)(acc[nb][r] * fac + scr[(m0 + lk * 4 + r) * SSTR + nb * 16 + lrow]);
        }
        t0 += len;
    }

    // ---- diagonal tile staging: grp0 -> K row-major, grp1 -> V^T ----
    __syncthreads();   // Hs (last range) visible; Kt/Vt free
    if (grp == 0) {
        bf16x4 w0 = {(bf16)P.kA0.x, (bf16)P.kA0.y, (bf16)P.kA0.z, (bf16)P.kA0.w};
        bf16x4 w1 = {(bf16)P.kA1.x, (bf16)P.kA1.y, (bf16)P.kA1.z, (bf16)P.kA1.w};
        bf16x4 w2 = {(bf16)P.kB0.x, (bf16)P.kB0.y, (bf16)P.kB0.z, (bf16)P.kB0.w};
        bf16x4 w3 = {(bf16)P.kB1.x, (bf16)P.kB1.y, (bf16)P.kB1.z, (bf16)P.kB1.w};
        *(bf16x4*)&Kt[0][(2 * jp) * LSTR + p0] = w0;
        *(bf16x4*)&Kt[0][(2 * jp) * LSTR + p0 + 4] = w1;
        *(bf16x4*)&Kt[0][(2 * jp + 1) * LSTR + p0] = w2;
        *(bf16x4*)&Kt[0][(2 * jp + 1) * LSTR + p0 + 4] = w3;
    } else {
        float vr0[8] = {P.vA0.x, P.vA0.y, P.vA0.z, P.vA0.w, P.vA1.x, P.vA1.y, P.vA1.z, P.vA1.w};
        float vr1[8] = {P.vB0.x, P.vB0.y, P.vB0.z, P.vB0.w, P.vB1.x, P.vB1.y, P.vB1.z, P.vB1.w};
#pragma unroll
        for (int i2 = 0; i2 < 8; ++i2) {
            bf16x2 vv = {(bf16)vr0[i2], (bf16)vr1[i2]};
            *(bf16x2*)&Vt[0][(p0 + i2) * LSTR + 2 * jp] = vv;
        }
    }
    __syncthreads();

    // ---- diagonal: S = Q K^T (each wave: 2 col-blocks cb = grp*2 + c) ----
    floatx4 sacc[2];
#pragma unroll
    for (int c = 0; c < 2; ++c) {
        const int cb = grp * 2 + c;
        bf16x8 b0 = *(bf16x8*)&Kt[0][(cb * 16 + lrow) * LSTR + lk * 8];
        bf16x8 b1 = *(bf16x8*)&Kt[0][(cb * 16 + lrow) * LSTR + 32 + lk * 8];
        floatx4 a = {0.f, 0.f, 0.f, 0.f};
        a = __builtin_amdgcn_mfma_f32_16x16x32_bf16(qa0, b0, a, 0, 0, 0);
        a = __builtin_amdgcn_mfma_f32_16x16x32_bf16(qa1, b1, a, 0, 0, 0);
        sacc[c] = a;
    }
    // per-element weight (levels 0..6) -> P (into Qs; rows by mw, cols by grp)
#pragma unroll
    for (int c = 0; c < 2; ++c) {
        const int jl = (grp * 2 + c) * 16 + lrow;
        const float csj = csS[rt * RT + jl];
#pragma unroll
        for (int r = 0; r < 4; ++r) {
            const int rowl = m0 + lk * 4 + r;
            float wgt = 0.f;
            if (jl <= rowl) {
                const int x = rowl ^ jl;
                const int lev0 = x ? (32 - __clz(x)) : 0;
                wgt = __expf(csr[r] - csj) * Lsh[lev0 * RT + rowl];
            }
            Qs[rowl * LSTR + jl] = (bf16)(sacc[c][r] * wgt);
        }
    }
    __syncthreads();   // P rows assembled from both groups' col-halves

    const bf16x8 pa0 = *(bf16x8*)&Qs[(m0 + lrow) * LSTR + lk * 8];
    const bf16x8 pa1 = *(bf16x8*)&Qs[(m0 + lrow) * LSTR + 32 + lk * 8];
    floatx4 O[2];
#pragma unroll
    for (int c = 0; c < 2; ++c) {
        const int cb = grp * 2 + c;
        bf16x8 b0 = *(bf16x8*)&Vt[0][(cb * 16 + lrow) * LSTR + lk * 8];
        bf16x8 b1 = *(bf16x8*)&Vt[0][(cb * 16 + lrow) * LSTR + 32 + lk * 8];
        floatx4 a = {0.f, 0.f, 0.f, 0.f};
        a = __builtin_amdgcn_mfma_f32_16x16x32_bf16(pa0, b0, a, 0, 0, 0);
        a = __builtin_amdgcn_mfma_f32_16x16x32_bf16(pa1, b1, a, 0, 0, 0);
        O[c] = a;
    }

    // ---- hierarchical levels 7..10 from Hs ----
#pragma unroll
    for (int s = 3; s >= 0; --s) {
        if (!((rt >> s) & 1)) continue;
        float wr[4];
#pragma unroll
        for (int r = 0; r < 4; ++r)
            wr[r] = Lw4[s * RT + m0 + lk * 4 + r] * __expf(csr[r] - eref4[s]);
#pragma unroll
        for (int c = 0; c < 2; ++c) {
            const int cb = grp * 2 + c;
            bf16x8 b0 = *(bf16x8*)&Hs[(s * RT + cb * 16 + lrow) * LSTR + lk * 8];
            bf16x8 b1 = *(bf16x8*)&Hs[(s * RT + cb * 16 + lrow) * LSTR + 32 + lk * 8];
            floatx4 a = {0.f, 0.f, 0.f, 0.f};
            a = __builtin_amdgcn_mfma_f32_16x16x32_bf16(qa0, b0, a, 0, 0, 0);
            a = __builtin_amdgcn_mfma_f32_16x16x32_bf16(qa1, b1, a, 0, 0, 0);
#pragma unroll
            for (int r = 0; r < 4; ++r) O[c][r] += wr[r] * a[r];
        }
    }

    // ---- epilogue: rows by mw strip, cols by grp half ----
#pragma unroll
    for (int r = 0; r < 4; ++r) {
        const int ig = rt * RT + m0 + lk * 4 + r;
        float* op = out + ((size_t)((b * TT + ig) * HH) + h) * DD;
#pragma unroll
        for (int c = 0; c < 2; ++c)
            op[(grp * 2 + c) * 16 + lrow] = O[c][r];
    }
}

extern "C" void kernel_launch(void* const* d_in, const int* in_sizes, int n_in,
                              void* d_out, int out_size, void* d_ws, size_t ws_size,
                              hipStream_t stream) {
    const float* q = (const float*)d_in[0];
    const float* k = (const float*)d_in[1];
    const float* v = (const float*)d_in[2];
    const float* g = (const float*)d_in[3];
    const float* L = (const float*)d_in[4];
    float* out = (float*)d_out;

    hattn_fused_kernel<<<BD * HH * NT, 512, 0, stream>>>(q, k, v, g, L, out);
}